// Round 2
// baseline (2208.942 us; speedup 1.0000x reference)
//
#include <hip/hip_runtime.h>
#include <cstdint>
#include <cstddef>

#define NROWS 32768
#define DDIM 256
#define KCODES 4096

// ---------------- ws layout (float offsets) ----------------
#define WS_LOSS 0
#define WS_BINS 1
#define WS_ESUM (1 + KCODES)
#define WS_N (WS_ESUM + KCODES * DDIM)
#define WS_XSQ (WS_N + 1)
#define WS_ESQ (WS_XSQ + NROWS)
#define WS_IDX (WS_ESQ + KCODES)

// gcc _mm512_reduce_add_ps pairing tree (numpy npyv_sum_f32 on AVX512)
__device__ __forceinline__ float hsum16_np(const float a[16]) {
    float t3[8];
#pragma unroll
    for (int m = 0; m < 8; ++m) t3[m] = __fadd_rn(a[m + 8], a[m]);
    float t6[4];
#pragma unroll
    for (int m = 0; m < 4; ++m) t6[m] = __fadd_rn(t3[m + 4], t3[m]);
    return __fadd_rn(__fadd_rn(t6[0], t6[2]), __fadd_rn(t6[1], t6[3]));
}

// numpy FLOAT_pairwise_sum of squares, 128-element SIMD block (AVX512):
// 8 zmm loads, lane-wise tree ((v0+v1)+(v2+v3))+((v4+v5)+(v6+v7)), horizontal gcc tree
__device__ __forceinline__ float np_sum_sq_128(const float* a) {
    float t[16];
#pragma unroll
    for (int l = 0; l < 16; ++l) {
        float m0 = __fmul_rn(a[l], a[l]);
        float m1 = __fmul_rn(a[16 + l], a[16 + l]);
        float m2 = __fmul_rn(a[32 + l], a[32 + l]);
        float m3 = __fmul_rn(a[48 + l], a[48 + l]);
        float m4 = __fmul_rn(a[64 + l], a[64 + l]);
        float m5 = __fmul_rn(a[80 + l], a[80 + l]);
        float m6 = __fmul_rn(a[96 + l], a[96 + l]);
        float m7 = __fmul_rn(a[112 + l], a[112 + l]);
        float s01 = __fadd_rn(m0, m1);
        float s23 = __fadd_rn(m2, m3);
        float s45 = __fadd_rn(m4, m5);
        float s67 = __fadd_rn(m6, m7);
        t[l] = __fadd_rn(__fadd_rn(s01, s23), __fadd_rn(s45, s67));
    }
    return hsum16_np(t);
}

__global__ void k_rownorm(const float* __restrict__ src, float* __restrict__ dst, int rows) {
    int r = blockIdx.x * blockDim.x + threadIdx.x;
    if (r < rows) {
        const float* p = src + ((size_t)r << 8);
        // numpy pairwise recursion: 256 -> 128 + 128
        dst[r] = __fadd_rn(np_sum_sq_128(p), np_sum_sq_128(p + 128));
    }
}

// fused dist + argmin. block tile: 32 rows x 64 cols, 256 threads, micro 2x4,
// 16 lane-accumulators per pair (mimics np.einsum single-vaccum FMA chain).
// launch_bounds (256,1): R0's (256,2) was taken as 2 blocks/CU -> 128-VGPR
// budget -> ~60 spilled regs -> 607 MB scratch writes/dispatch. (256,1)
// gives a >=256 VGPR budget; the ~190-reg working set fits, LDS (54KB)
// still allows 2 blocks/CU = 2 waves/SIMD.
__global__ __launch_bounds__(256, 1) void k_argmin(const float* __restrict__ x,
                                                   const float* __restrict__ embed,
                                                   const float* __restrict__ xsq,
                                                   const float* __restrict__ esq,
                                                   int* __restrict__ out_idx) {
    __shared__ float xs[32][260];  // full D staged once, pad keeps b128 2-way-free
    __shared__ float es[64][68];   // one 64-d chunk of the e-tile
    __shared__ unsigned long long red[32][16];

    const int tid = threadIdx.x;
    const int tc = tid & 15;
    const int tr = tid >> 4;
    const int n0 = blockIdx.x * 32;

#pragma unroll
    for (int p = 0; p < 8; ++p) {
        int v = tid + p * 256;
        int r = v >> 6;
        int c4 = (v & 63) << 2;
        const float4 f = *reinterpret_cast<const float4*>(x + ((size_t)(n0 + r) << 8) + c4);
        *reinterpret_cast<float4*>(&xs[r][c4]) = f;
    }

    const float xq0 = xsq[n0 + tr];
    const float xq1 = xsq[n0 + tr + 16];

    unsigned long long best0 = ~0ull, best1 = ~0ull;

    for (int kt = 0; kt < KCODES / 64; ++kt) {
        const int k0 = kt * 64;
        float acc[2][4][16];
#pragma unroll
        for (int i = 0; i < 2; ++i)
#pragma unroll
            for (int j = 0; j < 4; ++j)
#pragma unroll
                for (int l = 0; l < 16; ++l) acc[i][j][l] = 0.0f;

        for (int c = 0; c < 4; ++c) {
            __syncthreads();
#pragma unroll
            for (int p = 0; p < 4; ++p) {
                int v = tid + p * 256;
                int r = v >> 4;
                int c4 = (v & 15) << 2;
                const float4 f = *reinterpret_cast<const float4*>(
                    embed + ((size_t)(k0 + r) << 8) + (c << 6) + c4);
                *reinterpret_cast<float4*>(&es[r][c4]) = f;
            }
            __syncthreads();
            // np.einsum outstride0_two: groups of 4 vectors nested REVERSED (a3..a0)
#pragma unroll
            for (int jj = 3; jj >= 0; --jj) {
#pragma unroll
                for (int q = 0; q < 4; ++q) {
                    const int dl = ((c * 4 + jj) << 4) + (q << 2);
                    const int el = (jj << 4) + (q << 2);
                    const float4 a0 = *reinterpret_cast<const float4*>(&xs[tr][dl]);
                    const float4 a1 = *reinterpret_cast<const float4*>(&xs[tr + 16][dl]);
                    const int lb = q << 2;
#pragma unroll
                    for (int j2 = 0; j2 < 4; ++j2) {
                        const float4 b = *reinterpret_cast<const float4*>(&es[tc + 16 * j2][el]);
                        acc[0][j2][lb + 0] = __builtin_fmaf(a0.x, b.x, acc[0][j2][lb + 0]);
                        acc[0][j2][lb + 1] = __builtin_fmaf(a0.y, b.y, acc[0][j2][lb + 1]);
                        acc[0][j2][lb + 2] = __builtin_fmaf(a0.z, b.z, acc[0][j2][lb + 2]);
                        acc[0][j2][lb + 3] = __builtin_fmaf(a0.w, b.w, acc[0][j2][lb + 3]);
                        acc[1][j2][lb + 0] = __builtin_fmaf(a1.x, b.x, acc[1][j2][lb + 0]);
                        acc[1][j2][lb + 1] = __builtin_fmaf(a1.y, b.y, acc[1][j2][lb + 1]);
                        acc[1][j2][lb + 2] = __builtin_fmaf(a1.z, b.z, acc[1][j2][lb + 2]);
                        acc[1][j2][lb + 3] = __builtin_fmaf(a1.w, b.w, acc[1][j2][lb + 3]);
                    }
                }
            }
        }
#pragma unroll
        for (int j2 = 0; j2 < 4; ++j2) {
            const int kk = k0 + tc + 16 * j2;
            const float eq = esq[kk];
            {
                const float dot = hsum16_np(acc[0][j2]);
                const float dist = __fadd_rn(__fsub_rn(xq0, __fmul_rn(2.0f, dot)), eq);
                unsigned u = __float_as_uint(dist);
                u ^= (unsigned)((int)u >> 31) | 0x80000000u;
                const unsigned long long key = ((unsigned long long)u << 32) | (unsigned)kk;
                best0 = key < best0 ? key : best0;
            }
            {
                const float dot = hsum16_np(acc[1][j2]);
                const float dist = __fadd_rn(__fsub_rn(xq1, __fmul_rn(2.0f, dot)), eq);
                unsigned u = __float_as_uint(dist);
                u ^= (unsigned)((int)u >> 31) | 0x80000000u;
                const unsigned long long key = ((unsigned long long)u << 32) | (unsigned)kk;
                best1 = key < best1 ? key : best1;
            }
        }
    }

    __syncthreads();
    red[tr][tc] = best0;
    red[tr + 16][tc] = best1;
    __syncthreads();
    if (tid < 32) {
        unsigned long long m = red[tid][0];
#pragma unroll
        for (int t = 1; t < 16; ++t) {
            unsigned long long v = red[tid][t];
            m = v < m ? v : m;
        }
        out_idx[n0 + tid] = (int)(m & 0xFFFFFFFFu);
    }
}

__global__ void k_scatter(const float* __restrict__ x, const float* __restrict__ embed,
                          const int* __restrict__ idx, float* __restrict__ out,
                          float* __restrict__ loss_acc, float* __restrict__ bins,
                          float* __restrict__ esum, float* __restrict__ ind_out) {
    const int n = blockIdx.x;
    const int d = threadIdx.x;
    const int k = idx[n];
    const size_t xi = ((size_t)n << 8) + d;
    const float xv = x[xi];
    const float qv = embed[((size_t)k << 8) + d];
    const float diff = __fsub_rn(qv, xv);
    out[xi] = __fadd_rn(xv, diff);
    atomicAdd(&esum[((size_t)k << 8) + d], xv);
    __shared__ float sred[256];
    sred[d] = __fmul_rn(diff, diff);
    __syncthreads();
    for (int s = 128; s > 0; s >>= 1) {
        if (d < s) sred[d] += sred[d + s];
        __syncthreads();
    }
    if (d == 0) {
        atomicAdd(loss_acc, sred[0]);
        atomicAdd(&bins[k], 1.0f);
        ind_out[n] = (float)k;
    }
}

__global__ void k_cluster(const float* __restrict__ cs, const float* __restrict__ bins,
                          float* __restrict__ ncs_out, float* __restrict__ n_out) {
    __shared__ float sred[1024];
    const int t = threadIdx.x;
    float s = 0.0f;
    for (int k = t; k < KCODES; k += 1024) {
        const float ncs = __fadd_rn(__fmul_rn(cs[k], 0.1f), __fmul_rn(bins[k], 0.9f));
        ncs_out[k] = ncs;
        s += ncs;
    }
    sred[t] = s;
    __syncthreads();
    for (int w = 512; w > 0; w >>= 1) {
        if (t < w) sred[t] += sred[t + w];
        __syncthreads();
    }
    if (t == 0) n_out[0] = sred[0];
}

__global__ void k_norm(const float* __restrict__ ea, const float* __restrict__ esum,
                       const float* __restrict__ ncs, const float* __restrict__ nptr,
                       float* __restrict__ en_out) {
    const int i = blockIdx.x * 256 + threadIdx.x;
    const int k = i >> 8;
    const float n = nptr[0];
    const float ncsk = ncs[k];
    const float smoothed = (ncsk + 1e-5f) / (n + 4096.0f * 1e-5f) * n;
    const float nea = __fadd_rn(__fmul_rn(ea[i], 0.1f), __fmul_rn(esum[i], 0.9f));
    en_out[i] = nea / smoothed;
}

__global__ void k_loss(const float* __restrict__ acc, float* __restrict__ dst) {
    if (threadIdx.x == 0) dst[0] = acc[0] * (1.0f / 8388608.0f);
}

extern "C" void kernel_launch(void* const* d_in, const int* in_sizes, int n_in, void* d_out,
                              int out_size, void* d_ws, size_t ws_size, hipStream_t stream) {
    (void)in_sizes; (void)n_in; (void)out_size; (void)ws_size;
    const float* x = (const float*)d_in[0];
    const float* emb = (const float*)d_in[1];
    const float* cs = (const float*)d_in[2];
    const float* ea = (const float*)d_in[3];
    float* ws = (float*)d_ws;
    float* out = (float*)d_out;

    float* w_loss = ws + WS_LOSS;
    float* w_bins = ws + WS_BINS;
    float* w_esum = ws + WS_ESUM;
    float* w_n = ws + WS_N;
    float* w_xsq = ws + WS_XSQ;
    float* w_esq = ws + WS_ESQ;
    int* w_idx = (int*)(ws + WS_IDX);

    float* o_out = out;              // [N*D]
    float* o_loss = out + 8388608;   // [1]
    float* o_ind = out + 8388609;    // [N]
    float* o_ncs = out + 8421377;    // [K]
    float* o_en = out + 8425473;     // [K*D]

    // zero loss + bins + esum each call (deterministic across replays)
    hipMemsetAsync(d_ws, 0, (size_t)WS_N * sizeof(float), stream);

    k_rownorm<<<NROWS / 256, 256, 0, stream>>>(x, w_xsq, NROWS);
    k_rownorm<<<KCODES / 256, 256, 0, stream>>>(emb, w_esq, KCODES);
    k_argmin<<<NROWS / 32, 256, 0, stream>>>(x, emb, w_xsq, w_esq, w_idx);
    k_scatter<<<NROWS, 256, 0, stream>>>(x, emb, w_idx, o_out, w_loss, w_bins, w_esum, o_ind);
    k_cluster<<<1, 1024, 0, stream>>>(cs, w_bins, o_ncs, w_n);
    k_norm<<<(KCODES * DDIM) / 256, 256, 0, stream>>>(ea, w_esum, o_ncs, w_n, o_en);
    k_loss<<<1, 64, 0, stream>>>(w_loss, o_loss);
}

// Round 3
// 1725.077 us; speedup vs baseline: 1.2805x; 1.2805x over previous
//
#include <hip/hip_runtime.h>
#include <cstdint>
#include <cstddef>

#define NROWS 32768
#define DDIM 256
#define KCODES 4096

// ---------------- ws layout (float offsets) ----------------
#define WS_LOSS 0
#define WS_BINS 1
#define WS_ESUM (1 + KCODES)
#define WS_N (WS_ESUM + KCODES * DDIM)
#define WS_XSQ (WS_N + 1)
#define WS_ESQ (WS_XSQ + NROWS)
#define WS_IDX (WS_ESQ + KCODES)

// gcc _mm512_reduce_add_ps pairing tree (numpy npyv_sum_f32 on AVX512)
__device__ __forceinline__ float hsum16_np(const float a[16]) {
    float t3[8];
#pragma unroll
    for (int m = 0; m < 8; ++m) t3[m] = __fadd_rn(a[m + 8], a[m]);
    float t6[4];
#pragma unroll
    for (int m = 0; m < 4; ++m) t6[m] = __fadd_rn(t3[m + 4], t3[m]);
    return __fadd_rn(__fadd_rn(t6[0], t6[2]), __fadd_rn(t6[1], t6[3]));
}

// numpy FLOAT_pairwise_sum of squares, 128-element SIMD block (AVX512):
// 8 zmm loads, lane-wise tree ((v0+v1)+(v2+v3))+((v4+v5)+(v6+v7)), horizontal gcc tree
__device__ __forceinline__ float np_sum_sq_128(const float* a) {
    float t[16];
#pragma unroll
    for (int l = 0; l < 16; ++l) {
        float m0 = __fmul_rn(a[l], a[l]);
        float m1 = __fmul_rn(a[16 + l], a[16 + l]);
        float m2 = __fmul_rn(a[32 + l], a[32 + l]);
        float m3 = __fmul_rn(a[48 + l], a[48 + l]);
        float m4 = __fmul_rn(a[64 + l], a[64 + l]);
        float m5 = __fmul_rn(a[80 + l], a[80 + l]);
        float m6 = __fmul_rn(a[96 + l], a[96 + l]);
        float m7 = __fmul_rn(a[112 + l], a[112 + l]);
        float s01 = __fadd_rn(m0, m1);
        float s23 = __fadd_rn(m2, m3);
        float s45 = __fadd_rn(m4, m5);
        float s67 = __fadd_rn(m6, m7);
        t[l] = __fadd_rn(__fadd_rn(s01, s23), __fadd_rn(s45, s67));
    }
    return hsum16_np(t);
}

__global__ void k_rownorm(const float* __restrict__ src, float* __restrict__ dst, int rows) {
    int r = blockIdx.x * blockDim.x + threadIdx.x;
    if (r < rows) {
        const float* p = src + ((size_t)r << 8);
        // numpy pairwise recursion: 256 -> 128 + 128
        dst[r] = __fadd_rn(np_sum_sq_128(p), np_sum_sq_128(p + 128));
    }
}

// fused dist + argmin. block tile: 32 rows x 64 cols, 256 threads, micro 2x4,
// 16 lane-accumulators per pair (mimics np.einsum single-vaccum FMA chain).
//
// Occupancy history: (256,2) -> VGPR capped 128, ~60 regs spilled, 607MB
// scratch writes. (256,1) -> no spill (VGPR 148) but pinned to 1 block/CU
// (Occupancy 11.9%), dur regressed. HW ceiling at 148 VGPR is 2 waves/SIMD
// anyway (occupancy steps at 64/128/256), so ask for exactly min-2-waves/EU:
// VGPR budget 256 (no spill) AND 2 blocks/CU resident.
__global__ __attribute__((amdgpu_flat_work_group_size(256, 256), amdgpu_waves_per_eu(2)))
void k_argmin(const float* __restrict__ x,
              const float* __restrict__ embed,
              const float* __restrict__ xsq,
              const float* __restrict__ esq,
              int* __restrict__ out_idx) {
    __shared__ float xs[32][260];  // full D staged once, pad keeps b128 2-way-free
    __shared__ float es[64][68];   // one 64-d chunk of the e-tile; reused as argmin red buffer
    unsigned long long* red = (unsigned long long*)&es[0][0];  // 32*16*8B = 4KB <= es

    const int tid = threadIdx.x;
    const int tc = tid & 15;
    const int tr = tid >> 4;
    const int n0 = blockIdx.x * 32;

#pragma unroll
    for (int p = 0; p < 8; ++p) {
        int v = tid + p * 256;
        int r = v >> 6;
        int c4 = (v & 63) << 2;
        const float4 f = *reinterpret_cast<const float4*>(x + ((size_t)(n0 + r) << 8) + c4);
        *reinterpret_cast<float4*>(&xs[r][c4]) = f;
    }

    const float xq0 = xsq[n0 + tr];
    const float xq1 = xsq[n0 + tr + 16];

    unsigned long long best0 = ~0ull, best1 = ~0ull;

    for (int kt = 0; kt < KCODES / 64; ++kt) {
        const int k0 = kt * 64;
        float acc[2][4][16];
#pragma unroll
        for (int i = 0; i < 2; ++i)
#pragma unroll
            for (int j = 0; j < 4; ++j)
#pragma unroll
                for (int l = 0; l < 16; ++l) acc[i][j][l] = 0.0f;

        for (int c = 0; c < 4; ++c) {
            __syncthreads();
#pragma unroll
            for (int p = 0; p < 4; ++p) {
                int v = tid + p * 256;
                int r = v >> 4;
                int c4 = (v & 15) << 2;
                const float4 f = *reinterpret_cast<const float4*>(
                    embed + ((size_t)(k0 + r) << 8) + (c << 6) + c4);
                *reinterpret_cast<float4*>(&es[r][c4]) = f;
            }
            __syncthreads();
            // np.einsum outstride0_two: groups of 4 vectors nested REVERSED (a3..a0)
#pragma unroll
            for (int jj = 3; jj >= 0; --jj) {
#pragma unroll
                for (int q = 0; q < 4; ++q) {
                    const int dl = ((c * 4 + jj) << 4) + (q << 2);
                    const int el = (jj << 4) + (q << 2);
                    const float4 a0 = *reinterpret_cast<const float4*>(&xs[tr][dl]);
                    const float4 a1 = *reinterpret_cast<const float4*>(&xs[tr + 16][dl]);
                    const int lb = q << 2;
#pragma unroll
                    for (int j2 = 0; j2 < 4; ++j2) {
                        const float4 b = *reinterpret_cast<const float4*>(&es[tc + 16 * j2][el]);
                        acc[0][j2][lb + 0] = __builtin_fmaf(a0.x, b.x, acc[0][j2][lb + 0]);
                        acc[0][j2][lb + 1] = __builtin_fmaf(a0.y, b.y, acc[0][j2][lb + 1]);
                        acc[0][j2][lb + 2] = __builtin_fmaf(a0.z, b.z, acc[0][j2][lb + 2]);
                        acc[0][j2][lb + 3] = __builtin_fmaf(a0.w, b.w, acc[0][j2][lb + 3]);
                        acc[1][j2][lb + 0] = __builtin_fmaf(a1.x, b.x, acc[1][j2][lb + 0]);
                        acc[1][j2][lb + 1] = __builtin_fmaf(a1.y, b.y, acc[1][j2][lb + 1]);
                        acc[1][j2][lb + 2] = __builtin_fmaf(a1.z, b.z, acc[1][j2][lb + 2]);
                        acc[1][j2][lb + 3] = __builtin_fmaf(a1.w, b.w, acc[1][j2][lb + 3]);
                    }
                }
            }
        }
#pragma unroll
        for (int j2 = 0; j2 < 4; ++j2) {
            const int kk = k0 + tc + 16 * j2;
            const float eq = esq[kk];
            {
                const float dot = hsum16_np(acc[0][j2]);
                const float dist = __fadd_rn(__fsub_rn(xq0, __fmul_rn(2.0f, dot)), eq);
                unsigned u = __float_as_uint(dist);
                u ^= (unsigned)((int)u >> 31) | 0x80000000u;
                const unsigned long long key = ((unsigned long long)u << 32) | (unsigned)kk;
                best0 = key < best0 ? key : best0;
            }
            {
                const float dot = hsum16_np(acc[1][j2]);
                const float dist = __fadd_rn(__fsub_rn(xq1, __fmul_rn(2.0f, dot)), eq);
                unsigned u = __float_as_uint(dist);
                u ^= (unsigned)((int)u >> 31) | 0x80000000u;
                const unsigned long long key = ((unsigned long long)u << 32) | (unsigned)kk;
                best1 = key < best1 ? key : best1;
            }
        }
    }

    __syncthreads();  // all es reads done before aliasing as red
    red[tr * 16 + tc] = best0;
    red[(tr + 16) * 16 + tc] = best1;
    __syncthreads();
    if (tid < 32) {
        unsigned long long m = red[tid * 16];
#pragma unroll
        for (int t = 1; t < 16; ++t) {
            unsigned long long v = red[tid * 16 + t];
            m = v < m ? v : m;
        }
        out_idx[n0 + tid] = (int)(m & 0xFFFFFFFFu);
    }
}

__global__ void k_scatter(const float* __restrict__ x, const float* __restrict__ embed,
                          const int* __restrict__ idx, float* __restrict__ out,
                          float* __restrict__ loss_acc, float* __restrict__ bins,
                          float* __restrict__ esum, float* __restrict__ ind_out) {
    const int n = blockIdx.x;
    const int d = threadIdx.x;
    const int k = idx[n];
    const size_t xi = ((size_t)n << 8) + d;
    const float xv = x[xi];
    const float qv = embed[((size_t)k << 8) + d];
    const float diff = __fsub_rn(qv, xv);
    out[xi] = __fadd_rn(xv, diff);
    atomicAdd(&esum[((size_t)k << 8) + d], xv);
    __shared__ float sred[256];
    sred[d] = __fmul_rn(diff, diff);
    __syncthreads();
    for (int s = 128; s > 0; s >>= 1) {
        if (d < s) sred[d] += sred[d + s];
        __syncthreads();
    }
    if (d == 0) {
        atomicAdd(loss_acc, sred[0]);
        atomicAdd(&bins[k], 1.0f);
        ind_out[n] = (float)k;
    }
}

__global__ void k_cluster(const float* __restrict__ cs, const float* __restrict__ bins,
                          float* __restrict__ ncs_out, float* __restrict__ n_out) {
    __shared__ float sred[1024];
    const int t = threadIdx.x;
    float s = 0.0f;
    for (int k = t; k < KCODES; k += 1024) {
        const float ncs = __fadd_rn(__fmul_rn(cs[k], 0.1f), __fmul_rn(bins[k], 0.9f));
        ncs_out[k] = ncs;
        s += ncs;
    }
    sred[t] = s;
    __syncthreads();
    for (int w = 512; w > 0; w >>= 1) {
        if (t < w) sred[t] += sred[t + w];
        __syncthreads();
    }
    if (t == 0) n_out[0] = sred[0];
}

__global__ void k_norm(const float* __restrict__ ea, const float* __restrict__ esum,
                       const float* __restrict__ ncs, const float* __restrict__ nptr,
                       float* __restrict__ en_out) {
    const int i = blockIdx.x * 256 + threadIdx.x;
    const int k = i >> 8;
    const float n = nptr[0];
    const float ncsk = ncs[k];
    const float smoothed = (ncsk + 1e-5f) / (n + 4096.0f * 1e-5f) * n;
    const float nea = __fadd_rn(__fmul_rn(ea[i], 0.1f), __fmul_rn(esum[i], 0.9f));
    en_out[i] = nea / smoothed;
}

__global__ void k_loss(const float* __restrict__ acc, float* __restrict__ dst) {
    if (threadIdx.x == 0) dst[0] = acc[0] * (1.0f / 8388608.0f);
}

extern "C" void kernel_launch(void* const* d_in, const int* in_sizes, int n_in, void* d_out,
                              int out_size, void* d_ws, size_t ws_size, hipStream_t stream) {
    (void)in_sizes; (void)n_in; (void)out_size; (void)ws_size;
    const float* x = (const float*)d_in[0];
    const float* emb = (const float*)d_in[1];
    const float* cs = (const float*)d_in[2];
    const float* ea = (const float*)d_in[3];
    float* ws = (float*)d_ws;
    float* out = (float*)d_out;

    float* w_loss = ws + WS_LOSS;
    float* w_bins = ws + WS_BINS;
    float* w_esum = ws + WS_ESUM;
    float* w_n = ws + WS_N;
    float* w_xsq = ws + WS_XSQ;
    float* w_esq = ws + WS_ESQ;
    int* w_idx = (int*)(ws + WS_IDX);

    float* o_out = out;              // [N*D]
    float* o_loss = out + 8388608;   // [1]
    float* o_ind = out + 8388609;    // [N]
    float* o_ncs = out + 8421377;    // [K]
    float* o_en = out + 8425473;     // [K*D]

    // zero loss + bins + esum each call (deterministic across replays)
    hipMemsetAsync(d_ws, 0, (size_t)WS_N * sizeof(float), stream);

    k_rownorm<<<NROWS / 256, 256, 0, stream>>>(x, w_xsq, NROWS);
    k_rownorm<<<KCODES / 256, 256, 0, stream>>>(emb, w_esq, KCODES);
    k_argmin<<<NROWS / 32, 256, 0, stream>>>(x, emb, w_xsq, w_esq, w_idx);
    k_scatter<<<NROWS, 256, 0, stream>>>(x, emb, w_idx, o_out, w_loss, w_bins, w_esum, o_ind);
    k_cluster<<<1, 1024, 0, stream>>>(cs, w_bins, o_ncs, w_n);
    k_norm<<<(KCODES * DDIM) / 256, 256, 0, stream>>>(ea, w_esum, o_ncs, w_n, o_en);
    k_loss<<<1, 64, 0, stream>>>(w_loss, o_loss);
}